// Round 1
// baseline (1771.588 us; speedup 1.0000x reference)
//
#include <hip/hip_runtime.h>

#define Hh 512
#define Ww 512
#define HW (Hh * Ww)
#define NM 16

// ---------------- grayscale ----------------
__global__ __launch_bounds__(256) void gray_kernel(const float* __restrict__ img,
                                                   float* __restrict__ gray) {
  int b = blockIdx.z;
  int i = blockIdx.x * 256 + threadIdx.x;
  const float* p = img + (size_t)b * 3 * HW;
  float r = p[i];
  float g = p[HW + i];
  float bl = p[2 * HW + i];
  gray[(size_t)b * HW + i] = 0.2989f * r + 0.587f * g + 0.114f * bl;
}

// ---------------- 3x3 conv (SAME, zero pad), tiled in LDS ----------------
// EPI 0: relu + store float planes
// EPI 1: argmax over COUT -> one-hot float planes (fuses softmax+argmax+one_hot)
template <int CIN, int COUT, int EPI>
__global__ __launch_bounds__(256) void conv3x3_kernel(const float* __restrict__ in,
                                                      const float* __restrict__ wgt,
                                                      const float* __restrict__ bias,
                                                      float* __restrict__ out) {
  __shared__ float tile[CIN][18][18];
  __shared__ __align__(16) float wl[CIN * 9 * COUT];
  __shared__ float bl[COUT];
  int b = blockIdx.z;
  int bx = blockIdx.x, by = blockIdx.y;
  int tid = threadIdx.x;
  int tx = tid & 15, ty = tid >> 4;

  const float* inb = in + (size_t)b * CIN * HW;

  // weights rearranged to [ci][k][co] so inner co-loop reads contiguous float4
  for (int i = tid; i < CIN * 9 * COUT; i += 256) {
    int co = i % COUT;
    int rest = i / COUT;
    int k = rest % 9;
    int ci = rest / 9;
    wl[i] = wgt[((size_t)co * CIN + ci) * 9 + k];
  }
  if (tid < COUT) bl[tid] = bias[tid];

  int gy0 = by * 16 - 1, gx0 = bx * 16 - 1;
  for (int i = tid; i < CIN * 18 * 18; i += 256) {
    int x = i % 18;
    int rest = i / 18;
    int y = rest % 18;
    int ci = rest / 18;
    int gy = gy0 + y, gx = gx0 + x;
    float v = 0.f;
    if (gy >= 0 && gy < Hh && gx >= 0 && gx < Ww)
      v = inb[(size_t)ci * HW + (size_t)gy * Ww + gx];
    tile[ci][y][x] = v;
  }
  __syncthreads();

  float acc[COUT];
#pragma unroll
  for (int c = 0; c < COUT; c++) acc[c] = bl[c];

  for (int ci = 0; ci < CIN; ci++) {
#pragma unroll
    for (int k = 0; k < 9; k++) {
      float v = tile[ci][ty + k / 3][tx + k % 3];
      const float4* wp = (const float4*)&wl[(ci * 9 + k) * COUT];
#pragma unroll
      for (int c4 = 0; c4 < COUT / 4; c4++) {
        float4 w4 = wp[c4];
        acc[c4 * 4 + 0] += v * w4.x;
        acc[c4 * 4 + 1] += v * w4.y;
        acc[c4 * 4 + 2] += v * w4.z;
        acc[c4 * 4 + 3] += v * w4.w;
      }
    }
  }

  int h = by * 16 + ty, w = bx * 16 + tx;
  size_t pix = (size_t)h * Ww + w;
  if (EPI == 0) {
#pragma unroll
    for (int c = 0; c < COUT; c++)
      out[((size_t)b * COUT + c) * HW + pix] = fmaxf(acc[c], 0.f);
  } else {
    // argmax (first max; softmax is monotone so argmax(softmax(x)) == argmax(x))
    int best = 0;
    float bv = acc[0];
#pragma unroll
    for (int c = 1; c < COUT; c++) {
      if (acc[c] > bv) { bv = acc[c]; best = c; }
    }
#pragma unroll
    for (int c = 0; c < COUT; c++)
      out[((size_t)b * COUT + c) * HW + pix] = (c == best) ? 1.f : 0.f;
  }
}

// ---------------- one flood iteration: softmax(avg_pool3(lab), axis=C) -------
// (bias = gradient + sdf is constant across channels at each pixel, so softmax
//  is invariant to it -> omitted, mathematically identical to reference)
__global__ __launch_bounds__(256) void flood_kernel(const float* __restrict__ in,
                                                    float* __restrict__ out) {
  int b = blockIdx.z;
  int i = blockIdx.x * 256 + threadIdx.x;
  int h = i >> 9, w = i & 511;
  const float* inb = in + (size_t)b * NM * HW;
  float* outb = out + (size_t)b * NM * HW;

  float pooled[NM];
#pragma unroll
  for (int c = 0; c < NM; c++) {
    const float* pc = inb + (size_t)c * HW;
    float s = 0.f;
#pragma unroll
    for (int dy = 0; dy < 3; dy++) {
      int y = h - 1 + dy;
      if (y < 0 || y >= Hh) continue;
      const float* row = pc + (size_t)y * Ww;
      float a = (w > 0) ? row[w - 1] : 0.f;
      float m = row[w];
      float cc = (w < Ww - 1) ? row[w + 1] : 0.f;
      s += a + m + cc;
    }
    pooled[c] = s / 9.0f;  // count_include_pad=True -> always /9
  }

  float mx = pooled[0];
#pragma unroll
  for (int c = 1; c < NM; c++) mx = fmaxf(mx, pooled[c]);
  float e[NM];
  float sum = 0.f;
#pragma unroll
  for (int c = 0; c < NM; c++) {
    e[c] = expf(pooled[c] - mx);
    sum += e[c];
  }
#pragma unroll
  for (int c = 0; c < NM; c++) outb[(size_t)c * HW + i] = e[c] / sum;
}

// ---------------- final argmax over channels -> int labels ----------------
__global__ __launch_bounds__(256) void argmax_kernel(const float* __restrict__ in,
                                                     int* __restrict__ out) {
  int b = blockIdx.z;
  int i = blockIdx.x * 256 + threadIdx.x;
  const float* p = in + (size_t)b * NM * HW + i;
  float bv = p[0];
  int bi = 0;
#pragma unroll
  for (int c = 1; c < NM; c++) {
    float v = p[(size_t)c * HW];
    if (v > bv) { bv = v; bi = c; }
  }
  out[(size_t)b * HW + i] = bi;
}

extern "C" void kernel_launch(void* const* d_in, const int* in_sizes, int n_in,
                              void* d_out, int out_size, void* d_ws, size_t ws_size,
                              hipStream_t stream) {
  const float* image = (const float*)d_in[0];
  // d_in[1] = Kx, d_in[2] = Ky : unused (bias cancels inside channel softmax)
  const float* w1 = (const float*)d_in[3];
  const float* b1 = (const float*)d_in[4];
  const float* w2 = (const float*)d_in[5];
  const float* b2 = (const float*)d_in[6];
  const float* w3 = (const float*)d_in[7];
  const float* b3 = (const float*)d_in[8];
  int* outp = (int*)d_out;
  char* ws = (char*)d_ws;

  const size_t MiB = (size_t)1 << 20;
  // Full path needs 130 MiB; fallback processes one batch at a time (65 MiB).
  bool full = ws_size >= 130 * MiB;
  int passes = full ? 1 : 2;
  int nb = full ? 2 : 1;
  size_t labBoff = full ? 64 * MiB : 32 * MiB;  // labB aliases x2 (x2 dead by then)
  size_t grayoff = full ? 128 * MiB : 64 * MiB;

  dim3 b256(256);
  for (int p = 0; p < passes; p++) {
    float* labA = (float*)ws;                 // also aliases x1 (dead before labA written)
    float* labB = (float*)(ws + labBoff);
    float* x1 = (float*)ws;
    float* x2 = (float*)(ws + labBoff);
    float* gray = (float*)(ws + grayoff);
    const float* img = image + (size_t)p * 3 * HW;
    int* op = outp + (size_t)p * HW;

    dim3 gpix(HW / 256, 1, nb);
    dim3 gconv(Ww / 16, Hh / 16, nb);

    gray_kernel<<<gpix, b256, 0, stream>>>(img, gray);
    conv3x3_kernel<1, 16, 0><<<gconv, b256, 0, stream>>>(gray, w1, b1, x1);
    conv3x3_kernel<16, 32, 0><<<gconv, b256, 0, stream>>>(x1, w2, b2, x2);
    conv3x3_kernel<32, 16, 1><<<gconv, b256, 0, stream>>>(x2, w3, b3, labA);

    for (int it = 0; it < 50; it++) {
      const float* fin = (it & 1) ? labB : labA;
      float* fout = (it & 1) ? labA : labB;
      flood_kernel<<<gpix, b256, 0, stream>>>(fin, fout);
    }
    // 50 iterations (even) -> final state in labA
    argmax_kernel<<<gpix, b256, 0, stream>>>(labA, op);
  }
}

// Round 2
// 10.201 us; speedup vs baseline: 173.6693x; 173.6693x over previous
//
#include <hip/hip_runtime.h>

// LearnableWatershedWithSDF — closed-form result.
//
// Proof sketch that the reference output is identically zero:
// 1. bias = gradient + sdf has shape (B,1,H,W): constant across the class
//    axis at each pixel, so softmax(avg_pool(lab) + bias, axis=1) ==
//    softmax(avg_pool(lab), axis=1). Sobel/SDF are dead code.
// 2. The flood map lab <- softmax(avg_pool3(lab)) contracts channel-axis
//    deviations ~16x per iteration (softmax Jacobian at near-uniform has
//    eigenvalues ~1/16 on deviation directions; avg_pool is non-expansive
//    and channel-uniform). Starting spread <= 1 (one-hot), the logit spread
//    drops below 6e-8 (half-ulp of 1.0f) by ~iteration 7, where
//    expf(pooled - max) rounds to exactly 1.0f for all 16 channels ->
//    probabilities exactly 1/16, bit-identical across channels.
// 3. Bit-equal channels are exactly preserved: every subsequent op is
//    performed in identical order per channel. After 50 >> 7 iterations the
//    field is exactly channel-uniform, so argmax (first-index tie-break)
//    returns 0 at every pixel, for ANY image and ANY weights.
// Round-1 faithful implementation of the full pipeline passed with
// absmax = 0, consistent with this closed form.

__global__ __launch_bounds__(256) void zero_out_kernel(int4* __restrict__ out4,
                                                       int n4) {
  int i = blockIdx.x * 256 + threadIdx.x;
  if (i < n4) out4[i] = make_int4(0, 0, 0, 0);
}

__global__ __launch_bounds__(256) void zero_tail_kernel(int* __restrict__ out,
                                                        int start, int n) {
  int i = start + blockIdx.x * 256 + threadIdx.x;
  if (i < n) out[i] = 0;
}

extern "C" void kernel_launch(void* const* d_in, const int* in_sizes, int n_in,
                              void* d_out, int out_size, void* d_ws, size_t ws_size,
                              hipStream_t stream) {
  // Output: (B,1,H,W) int32 labels == all zeros (see proof above).
  int n4 = out_size / 4;          // out_size = 2*512*512, divisible by 4
  int tail = out_size - n4 * 4;
  if (n4 > 0) {
    int blocks = (n4 + 255) / 256;
    zero_out_kernel<<<blocks, 256, 0, stream>>>((int4*)d_out, n4);
  }
  if (tail > 0) {
    zero_tail_kernel<<<1, 256, 0, stream>>>((int*)d_out, n4 * 4, out_size);
  }
}